// Round 7
// baseline (189.487 us; speedup 1.0000x reference)
//
#include <hip/hip_runtime.h>
#include <math.h>
#include <stdint.h>

// Problem constants (B=2, S=2048, D=1024, H=16, HD=64)
constexpr int BB  = 2;
constexpr int SS  = 2048;
constexpr int DD  = 1024;
constexpr int HH  = 16;
constexpr int HDD = 64;
constexpr int MM  = BB * SS; // 4096

typedef uint16_t u16;
typedef __attribute__((ext_vector_type(4))) float    f32x4;
typedef __attribute__((ext_vector_type(8))) _Float16 f16x8;
typedef __attribute__((ext_vector_type(4))) _Float16 f16x4;
typedef __attribute__((ext_vector_type(8))) short    s16x8;
typedef __attribute__((ext_vector_type(4))) unsigned int u32x4;

__device__ __forceinline__ u16 to_f16(float f) {
    const _Float16 h = (_Float16)f;          // v_cvt_f16_f32, RNE
    return __builtin_bit_cast(u16, h);
}

__device__ __forceinline__ f32x4 mfma32(s16x8 a, s16x8 b, f32x4 c) {
    return __builtin_amdgcn_mfma_f32_16x16x32_f16(
        __builtin_bit_cast(f16x8, a), __builtin_bit_cast(f16x8, b), c, 0, 0, 0);
}
__device__ __forceinline__ f32x4 mfma32_ff(s16x8 a, f16x8 b, f32x4 c) {
    return __builtin_amdgcn_mfma_f32_16x16x32_f16(
        __builtin_bit_cast(f16x8, a), b, c, 0, 0, 0);
}

// async global->LDS, 16B per lane; LDS dest = wave-uniform base + lane*16
__device__ __forceinline__ void load_lds16(const void* g, void* l) {
    __builtin_amdgcn_global_load_lds(
        (const __attribute__((address_space(1))) void*)g,
        (__attribute__((address_space(3))) void*)l, 16, 0, 0);
}

// ---------------------------------------------------------------------------
// fp32 -> fp16 cast, all 5 tensors in one launch.
// blocks 0..2047: x (4M elems); blocks 2048..4095: wq,wk,wv,wo (1M each).
// ---------------------------------------------------------------------------
__global__ __launch_bounds__(256) void cast_all(
    const float* __restrict__ x,
    const float* __restrict__ w0, const float* __restrict__ w1,
    const float* __restrict__ w2, const float* __restrict__ w3,
    u16* __restrict__ xb, u16* __restrict__ wb)
{
    const int blk = blockIdx.x, tid = threadIdx.x;
    const float* src; u16* dst; int idx;
    if (blk < 2048) { src = x; dst = xb; idx = blk * 256 + tid; }
    else {
        const int b2 = blk - 2048, which = b2 >> 9;
        src = (which == 0) ? w0 : (which == 1) ? w1 : (which == 2) ? w2 : w3;
        dst = wb + ((size_t)which << 20);
        idx = (b2 & 511) * 256 + tid;
    }
    const float4* in4 = (const float4*)src;
    const float4 a = in4[idx * 2], b = in4[idx * 2 + 1];
    s16x8 v;
    v[0] = (short)to_f16(a.x); v[1] = (short)to_f16(a.y);
    v[2] = (short)to_f16(a.z); v[3] = (short)to_f16(a.w);
    v[4] = (short)to_f16(b.x); v[5] = (short)to_f16(b.y);
    v[6] = (short)to_f16(b.z); v[7] = (short)to_f16(b.w);
    *(s16x8*)(dst + (size_t)idx * 8) = v;
}

// ---------------------------------------------------------------------------
// Group K-loop, BK=64: same staged bytes / ds_read bytes / MFMA count per K
// as BK=32, but HALF the barrier iterations (8 vs 16 per group). R3 verified.
// LDS layout per group: [buf][128 rows][8 x 16B units]; physical unit pu
// at row r holds global unit pu ^ (r&7) -> frag ds_read_b128 is 2-way max.
// ---------------------------------------------------------------------------
template <bool SWAP>
__device__ __forceinline__ void kloop64(
    const u16* __restrict__ Ag, const u16* __restrict__ Wg,
    u16* Abase, u16* Bbase, const int w4,
    const int lane, const int wm, const int wn, f32x4 (&acc)[4][4])
{
    const int lt = lane & 15, quad = lane >> 4;
    const int cb = w4 * 4;                      // wave's first chunk

#define STG64(buf_, ko_) do {                                              \
    _Pragma("unroll")                                                      \
    for (int c = 0; c < 4; ++c) {                                          \
        load_lds16(Ag + (size_t)((cb + c) * 8) * 1024 + (ko_),             \
                   Abase + (buf_) * 8192 + (cb + c) * 512);                \
        load_lds16(Wg + (size_t)((cb + c) * 8) * 1024 + (ko_),             \
                   Bbase + (buf_) * 8192 + (cb + c) * 512);                \
    } } while (0)

    STG64(0, 0);                                 // prologue -> buffer 0

#pragma unroll 1
    for (int it = 0; it < 8; ++it) {
        const int buf = it & 1;
        __syncthreads();                         // drains this buffer's loads
        if (it < 7) STG64(buf ^ 1, (it + 1) * 64);
        const u16* Acur = Abase + buf * 8192;
        const u16* Bcur = Bbase + buf * 8192;

        s16x8 af[2][4], bf[2][4];
#pragma unroll
        for (int kk = 0; kk < 2; ++kk) {
#pragma unroll
            for (int i = 0; i < 4; ++i) {
                const int row = wm + i * 16 + lt;
                af[kk][i] = *(const s16x8*)(Acur + row * 64 +
                                (((kk * 4 + quad) ^ (row & 7)) * 8));
            }
#pragma unroll
            for (int j = 0; j < 4; ++j) {
                const int row = wn + j * 16 + lt;
                bf[kk][j] = *(const s16x8*)(Bcur + row * 64 +
                                (((kk * 4 + quad) ^ (row & 7)) * 8));
            }
        }
#pragma unroll
        for (int i = 0; i < 4; ++i)
#pragma unroll
            for (int j = 0; j < 4; ++j) {
                if (SWAP) {
                    acc[i][j] = mfma32(bf[0][j], af[0][i], acc[i][j]);
                    acc[i][j] = mfma32(bf[1][j], af[1][i], acc[i][j]);
                } else {
                    acc[i][j] = mfma32(af[0][i], bf[0][j], acc[i][j]);
                    acc[i][j] = mfma32(af[1][i], bf[1][j], acc[i][j]);
                }
            }
    }
#undef STG64
}

// ---------------------------------------------------------------------------
// Split-K MFMA GEMM: C = A @ W^T + bias.  A:[M,K] f16, W:[N,K] f16.
// 512 threads = 2 groups x 4 waves; group g computes K-half g (KH=512,
// 8 BK=64 iters) into fp32 partials; merged via a conflict-free LDS
// overlay; group 0 runs the epilogue.
// Grid mapping: IDENTITY (R6-verified). The R3-R5 "T1" swizzle chunked each
// XCD across ALL 24 W-panels (6MB > 4MB L2) -> FETCH doubled 40->80MB.
// Default round-robin keeps each XCD's W+A set < 4MB L2.
// MODE 1 (QKV): Q (SWAP) pre-scaled by 0.125 (exact pow2; do NOT fold
// log2e -- R4 numerics failure); K (SWAP) unscaled; V (no swap) written
// [B,H,HD,S] with kv-perm baked into each 64-wide s-tile.
// MODE 0 (SWAP): single matrix, fp32 [M,N] out, float4 stores.
// ---------------------------------------------------------------------------
template <int MODE>
__global__ __launch_bounds__(512) void gemm_mfma(
    const u16* __restrict__ A, const u16* __restrict__ Wb,
    const float* __restrict__ b0, const float* __restrict__ b1,
    const float* __restrict__ b2,
    float* __restrict__ outf, u16* __restrict__ outq, u16* __restrict__ outv)
{
    // 128KB: A [grp][buf][128x64] (64KB) | B same (64KB); fp32 overlay reuses
    __shared__ u16 smem[65536];

    const int tid = threadIdx.x, lane = tid & 63, wid = tid >> 6;
    const int grp = wid >> 2, w4 = wid & 3;
    const int quad = lane >> 4;

    const int bm = blockIdx.y * 128;
    const int nb = blockIdx.x * 128;      // col in (possibly concatenated) N space
    const int which = nb >> 10;           // 0..2 in MODE 1, always 0 in MODE 0
    const int ncol  = nb & 1023;
    const u16* Wblk = Wb + ((size_t)which << 20) + (size_t)ncol * 1024;

    // staging per-thread base (see kloop64 header)
    const int rbase = lane >> 3;
    const int gu    = (lane & 7) ^ rbase;
    const u16* Ag = A    + (size_t)(bm + rbase) * 1024 + grp * 512 + gu * 8;
    const u16* Wg = Wblk + (size_t)rbase        * 1024 + grp * 512 + gu * 8;
    u16* Abase = smem + grp * 16384;
    u16* Bbase = smem + 32768 + grp * 16384;

    f32x4 acc[4][4];
#pragma unroll
    for (int i = 0; i < 4; ++i)
#pragma unroll
        for (int j = 0; j < 4; ++j) { f32x4 z = {0.f, 0.f, 0.f, 0.f}; acc[i][j] = z; }

    const int wm = (w4 >> 1) * 64, wn = (w4 & 1) * 64;
    const bool swap = (MODE == 0) || (which < 2);
    if (swap) kloop64<true >(Ag, Wg, Abase, Bbase, w4, lane, wm, wn, acc);
    else      kloop64<false>(Ag, Wg, Abase, Bbase, w4, lane, wm, wn, acc);

    // ---- merge K-half partials via LDS overlay (exact fp32 adds) ----
    __syncthreads();   // all staging reads done; safe to overlay smem
    float* rp = (float*)smem;
    const int slot = (w4 * 64 + lane) * 4;
    if (grp == 1) {
#pragma unroll
        for (int i = 0; i < 4; ++i)
#pragma unroll
            for (int j = 0; j < 4; ++j)
                *(f32x4*)(rp + (i * 4 + j) * 1024 + slot) = acc[i][j];
    }
    __syncthreads();
    if (grp != 0) return;
#pragma unroll
    for (int i = 0; i < 4; ++i)
#pragma unroll
        for (int j = 0; j < 4; ++j)
            acc[i][j] += *(const f32x4*)(rp + (i * 4 + j) * 1024 + slot);

    if (MODE == 0) {
        // C^T: rows = n (tile j, quad*4+r), cols = m (tile i, lane&15)
#pragma unroll
        for (int j = 0; j < 4; ++j) {
            const int n0 = nb + wn + 16 * j + quad * 4;
            const float4 bv = *(const float4*)&b0[n0];
#pragma unroll
            for (int i = 0; i < 4; ++i) {
                const int m = bm + wm + 16 * i + (lane & 15);
                f32x4 w = acc[i][j];
                w[0] += bv.x; w[1] += bv.y; w[2] += bv.z; w[3] += bv.w;
                *(f32x4*)&outf[(size_t)m * 1024 + n0] = w;
            }
        }
    } else if (which < 2) {
        // Q/K (swapped): 4 contiguous hd per lane -> f16x4 stores
        const float* bias = which ? b1 : b0;
        const float scale = which ? 1.0f : 0.125f;   // fold 1/sqrt(HD) into Q
        u16* outb = outq + ((size_t)which << 22);
        const int h = (ncol + wn) >> 6;
#pragma unroll
        for (int j = 0; j < 4; ++j) {
            const int nl0 = ncol + wn + 16 * j + quad * 4;
            const float4 bv = *(const float4*)&bias[nl0];
            const int hd0 = 16 * j + quad * 4;
#pragma unroll
            for (int i = 0; i < 4; ++i) {
                const int m = bm + wm + 16 * i + (lane & 15);
                const int b_ = m >> 11, s = m & 2047;
                f16x4 w;
                w[0] = (_Float16)((acc[i][j][0] + bv.x) * scale);
                w[1] = (_Float16)((acc[i][j][1] + bv.y) * scale);
                w[2] = (_Float16)((acc[i][j][2] + bv.z) * scale);
                w[3] = (_Float16)((acc[i][j][3] + bv.w) * scale);
                *(f16x4*)&outb[(((size_t)(b_ * HH + h)) * SS + s) * HDD + hd0] = w;
            }
        }
    } else {
        // V (unswapped): rows = s (kv), cols = hd. kv = i*16 + quad*4 + r
        // -> p = (i>>1)*32 + quad*8 + (i&1)*4 + r (contiguous in r).
        const int kt = ((bm + wm) & 2047) >> 6;
        const int b_ = (bm + wm) >> 11;
#pragma unroll
        for (int j = 0; j < 4; ++j) {
            const int nl = ncol + wn + 16 * j + (lane & 15);
            const float bb = b2[nl];
            const int h = nl >> 6, hd = nl & 63;
            u16* vrow = outv + (((size_t)(b_ * HH + h)) * HDD + hd) * SS + kt * 64;
#pragma unroll
            for (int i = 0; i < 4; ++i) {
                const int p0 = (i >> 1) * 32 + quad * 8 + (i & 1) * 4;
                f16x4 w;
                w[0] = (_Float16)(acc[i][j][0] + bb);
                w[1] = (_Float16)(acc[i][j][1] + bb);
                w[2] = (_Float16)(acc[i][j][2] + bb);
                w[3] = (_Float16)(acc[i][j][3] + bb);
                *(f16x4*)&vrow[p0] = w;
            }
        }
    }
}

// ---------------------------------------------------------------------------
// MFMA flash attention v4 (R7): T15 double-pipeline. Transposed-S, no
// max-subtraction, in-block kv-split, XCD-grouped block swizzle (R6: FETCH
// 69.7->12.3MB). NEW: P(kt-1) is carried in registers; iteration kt runs
// QK(kt) -> exp/pack(kt) -> {l,PV}(kt-1), so the 32-exp VALU chain and the
// 20 PV/l MFMAs are independent within one basic block -> scheduler fills
// the MFMA shadow with exp VALU (R6 counters: MfmaUtil 35 + VALUBusy 43,
// phase-locked alternation; ideal overlap floor ~max of the two).
// V is ring-3 buffered (PV reads slot (kt-1)%3, prefetch writes (kt+1)%3 --
// disjoint); K stays double-buffered. LDS 80KB = exactly 2 blocks/CU.
// ---------------------------------------------------------------------------
__global__ __launch_bounds__(512, 4) void attn_mfma(
    const u16* __restrict__ Q, const u16* __restrict__ Kg,
    const u16* __restrict__ Vt, u16* __restrict__ ctx)
{
    // 80KB: K [grp][2][64x64] (32KB) + V [grp][3][64x64] (48KB); epilogue
    // overlays the front of it (35KB) after the last PV read.
    __shared__ u16 smem[40960];

    const int tid = threadIdx.x, lane = tid & 63, wid = tid >> 6;
    const int grp = wid >> 2, w4 = wid & 3;
    const int quad = lane >> 4;

    // bijective XCD-group swizzle: 512 blocks = 8 XCD x (4 heads x 16 qb)
    const int orig   = blockIdx.y * 16 + blockIdx.x;
    const int xcd    = orig & 7, within = orig >> 3;
    const int bh     = xcd * 4 + (within >> 4);
    const int q0     = (within & 15) * 128;

    const u16* Qb = Q  + (size_t)bh * SS * HDD;
    const u16* Kb = Kg + (size_t)bh * SS * HDD + (size_t)grp * 1024 * HDD;
    const u16* Vb = Vt + (size_t)bh * HDD * SS + grp * 1024;

    u16* Kbase = smem + grp * 8192;              // + kbuf*4096
    u16* Vbase = smem + 16384 + grp * 12288;     // + slot*4096 (ring-3)

    // Q B-frags for two q-subtiles: n=q=lane&15, k=quad*8+{0..7} (+32 chunk 1)
    const int qa = q0 + w4 * 32 + (lane & 15);
    const s16x8 bq0a = *(const s16x8*)(Qb + (size_t)qa * HDD + quad * 8);
    const s16x8 bq1a = *(const s16x8*)(Qb + (size_t)qa * HDD + 32 + quad * 8);
    const s16x8 bq0b = *(const s16x8*)(Qb + (size_t)(qa + 16) * HDD + quad * 8);
    const s16x8 bq1b = *(const s16x8*)(Qb + (size_t)(qa + 16) * HDD + 32 + quad * 8);

    f32x4 oa[4], ob[4];   // O^T: C[m=hd(16m + quad*4+r)][n=q=lane&15]
    f32x4 la4 = {0.f, 0.f, 0.f, 0.f}, lb4 = {0.f, 0.f, 0.f, 0.f};
#pragma unroll
    for (int m = 0; m < 4; ++m) {
        f32x4 z = {0.f, 0.f, 0.f, 0.f};
        oa[m] = z; ob[m] = z;
    }
    const s16x8 ones = {15360, 15360, 15360, 15360,
                        15360, 15360, 15360, 15360};  // f16 1.0 x8

    // staging: chunk c (0..7) = 1KB = 8 rows of 128B;
    // physical unit p=c*64+lane -> row p>>3, holds global unit (lane&7)^(row&7)
    const int c0 = w4 * 2, c1 = c0 + 1;
    const int r0 = (c0 * 64 + lane) >> 3, lu0 = ((lane & 7) ^ (r0 & 7));
    const int r1 = (c1 * 64 + lane) >> 3, lu1 = ((lane & 7) ^ (r1 & 7));
    const u16* Kp0 = Kb + (size_t)r0 * HDD + lu0 * 8;
    const u16* Kp1 = Kb + (size_t)r1 * HDD + lu1 * 8;
    const u16* Vp0 = Vb + (size_t)r0 * SS + lu0 * 8;
    const u16* Vp1 = Vb + (size_t)r1 * SS + lu1 * 8;

    // carried P (prev iteration's packed probabilities)
    f16x8 pA0, pA1, pB0, pB1;

    // ---- helpers ----
    f32x4 Sa[4], Sb[4];
    auto qk_tiles = [&](const u16* Kbuf) {
#pragma unroll
        for (int j = 0; j < 4; ++j) {
            const int row = j * 16 + (lane & 15);       // key row in tile
            const int sw = lane & 7;
            const s16x8 ak0 = *(const s16x8*)(Kbuf + (size_t)row * 64 + ((quad    ) ^ sw) * 8);
            const s16x8 ak1 = *(const s16x8*)(Kbuf + (size_t)row * 64 + ((quad + 4) ^ sw) * 8);
            f32x4 za = {0.f, 0.f, 0.f, 0.f};
            za = mfma32(ak0, bq0a, za);
            za = mfma32(ak1, bq1a, za);
            Sa[j] = za;
            f32x4 zb = {0.f, 0.f, 0.f, 0.f};
            zb = mfma32(ak0, bq0b, zb);
            zb = mfma32(ak1, bq1b, zb);
            Sb[j] = zb;
        }
    };
    auto exp_pack = [&](const f32x4* S, f16x8& o0, f16x8& o1) {
        u32x4 u;
        u[0] = __builtin_bit_cast(unsigned int, __builtin_amdgcn_cvt_pkrtz(__expf(S[0][0]), __expf(S[0][1])));
        u[1] = __builtin_bit_cast(unsigned int, __builtin_amdgcn_cvt_pkrtz(__expf(S[0][2]), __expf(S[0][3])));
        u[2] = __builtin_bit_cast(unsigned int, __builtin_amdgcn_cvt_pkrtz(__expf(S[1][0]), __expf(S[1][1])));
        u[3] = __builtin_bit_cast(unsigned int, __builtin_amdgcn_cvt_pkrtz(__expf(S[1][2]), __expf(S[1][3])));
        o0 = __builtin_bit_cast(f16x8, u);
        u[0] = __builtin_bit_cast(unsigned int, __builtin_amdgcn_cvt_pkrtz(__expf(S[2][0]), __expf(S[2][1])));
        u[1] = __builtin_bit_cast(unsigned int, __builtin_amdgcn_cvt_pkrtz(__expf(S[2][2]), __expf(S[2][3])));
        u[2] = __builtin_bit_cast(unsigned int, __builtin_amdgcn_cvt_pkrtz(__expf(S[3][0]), __expf(S[3][1])));
        u[3] = __builtin_bit_cast(unsigned int, __builtin_amdgcn_cvt_pkrtz(__expf(S[3][2]), __expf(S[3][3])));
        o1 = __builtin_bit_cast(f16x8, u);
    };
    auto do_pv = [&](const u16* Vbuf) {
        la4 = mfma32_ff(ones, pA0, la4);
        la4 = mfma32_ff(ones, pA1, la4);
        lb4 = mfma32_ff(ones, pB0, lb4);
        lb4 = mfma32_ff(ones, pB1, lb4);
#pragma unroll
        for (int m = 0; m < 4; ++m) {
            const int row = m * 16 + (lane & 15);       // hd row in Vt tile
            const int sw = lane & 7;
            const s16x8 v0 = *(const s16x8*)(Vbuf + (size_t)row * 64 + ((quad    ) ^ sw) * 8);
            const s16x8 v1 = *(const s16x8*)(Vbuf + (size_t)row * 64 + ((quad + 4) ^ sw) * 8);
            oa[m] = mfma32_ff(v0, pA0, oa[m]);
            oa[m] = mfma32_ff(v1, pA1, oa[m]);
            ob[m] = mfma32_ff(v0, pB0, ob[m]);
            ob[m] = mfma32_ff(v1, pB1, ob[m]);
        }
    };

    // prologue: tile 0 -> K buf0, V slot0
    load_lds16(Kp0, Kbase + c0 * 512);
    load_lds16(Kp1, Kbase + c1 * 512);
    load_lds16(Vp0, Vbase + c0 * 512);
    load_lds16(Vp1, Vbase + c1 * 512);

    // ---- peeled kt = 0: QK + exp only (no PV yet) ----
    __syncthreads();
    load_lds16(Kp0 + 64 * HDD, Kbase + 4096 + c0 * 512);   // K(1) -> buf1
    load_lds16(Kp1 + 64 * HDD, Kbase + 4096 + c1 * 512);
    load_lds16(Vp0 + 64,       Vbase + 4096 + c0 * 512);   // V(1) -> slot1
    load_lds16(Vp1 + 64,       Vbase + 4096 + c1 * 512);
    qk_tiles(Kbase);
    exp_pack(Sa, pA0, pA1);
    exp_pack(Sb, pB0, pB1);

    int sl_prev = 0, sl_next = 2;   // (kt-1)%3, (kt+1)%3 at kt=1
#pragma unroll 1
    for (int kt = 1; kt < 16; ++kt) {
        const int kb = kt & 1;
        __syncthreads();   // drains tile kt's loads (in flight one iter)
        if (kt < 15) {     // prefetch tile kt+1
            load_lds16(Kp0 + (size_t)(kt + 1) * 64 * HDD, Kbase + (kb ^ 1) * 4096 + c0 * 512);
            load_lds16(Kp1 + (size_t)(kt + 1) * 64 * HDD, Kbase + (kb ^ 1) * 4096 + c1 * 512);
            load_lds16(Vp0 + (kt + 1) * 64, Vbase + sl_next * 4096 + c0 * 512);
            load_lds16(Vp1 + (kt + 1) * 64, Vbase + sl_next * 4096 + c1 * 512);
        }
        // QK(kt): S depends only on K(kt) + Q regs
        qk_tiles(Kbase + kb * 4096);
        // exp/pack(kt) into temps -- independent of PV(kt-1) below, so the
        // scheduler can overlap this VALU chain with the 20 MFMAs
        f16x8 nA0, nA1, nB0, nB1;
        exp_pack(Sa, nA0, nA1);
        exp_pack(Sb, nB0, nB1);
        // l + PV for iteration kt-1 (carried P, V slot (kt-1)%3)
        do_pv(Vbase + sl_prev * 4096);
        // commit carried P
        pA0 = nA0; pA1 = nA1; pB0 = nB0; pB1 = nB1;
        sl_prev = (sl_prev == 2) ? 0 : sl_prev + 1;
        sl_next = (sl_next == 2) ? 0 : sl_next + 1;
    }
    // tail: PV(15). V(15) sits in slot 15%3 == 0 == sl_prev after loop.
    do_pv(Vbase);

    // ---- cross-group merge via LDS (plain sums; no-max softmax) ----
    // layout: float O[slot=w4*2+sub][q=16][hd=64 pad->68], then l[slot][16]
    __syncthreads();   // all PV reads done; safe to overlay smem
    float* ep = (float*)smem;
    float* lp = ep + 8 * 1088;
    if (grp == 1) {
#pragma unroll
        for (int sub = 0; sub < 2; ++sub) {
            const float* src = (sub == 0) ? (const float*)&oa[0] : (const float*)&ob[0];
            float* base = ep + (w4 * 2 + sub) * 1088 + (lane & 15) * 68 + quad * 4;
#pragma unroll
            for (int m = 0; m < 4; ++m)
                *(f32x4*)(base + m * 16) = *(const f32x4*)(src + m * 4);
        }
        if (quad == 0) {
            lp[(w4 * 2 + 0) * 16 + (lane & 15)] = la4[0];
            lp[(w4 * 2 + 1) * 16 + (lane & 15)] = lb4[0];
        }
    }
    __syncthreads();
    if (grp == 0) {
        const int b_ = bh >> 4, h = bh & 15;
#pragma unroll
        for (int sub = 0; sub < 2; ++sub) {
            const f32x4* own = (sub == 0) ? &oa[0] : &ob[0];
            const float lown = (sub == 0) ? la4[0] : lb4[0];
            const float inv = 1.f / (lown + lp[(w4 * 2 + sub) * 16 + (lane & 15)]);
            const float* base = ep + (w4 * 2 + sub) * 1088 + (lane & 15) * 68 + quad * 4;
            const int s_idx = q0 + w4 * 32 + sub * 16 + (lane & 15);
            u16* orow = ctx + ((size_t)(b_ * SS + s_idx)) * DD + h * HDD;
#pragma unroll
            for (int m = 0; m < 4; ++m) {
                const f32x4 part = *(const f32x4*)(base + m * 16);
                f16x4 w;
#pragma unroll
                for (int r = 0; r < 4; ++r)
                    w[r] = (_Float16)((own[m][r] + part[r]) * inv);
                *(f16x4*)(orow + m * 16 + quad * 4) = w;
            }
        }
    }
}

// ---------------------------------------------------------------------------
extern "C" void kernel_launch(void* const* d_in, const int* in_sizes, int n_in,
                              void* d_out, int out_size, void* d_ws, size_t ws_size,
                              hipStream_t stream)
{
    const float* x  = (const float*)d_in[0];
    const float* wq = (const float*)d_in[1];
    const float* bq = (const float*)d_in[2];
    const float* wk = (const float*)d_in[3];
    const float* bk = (const float*)d_in[4];
    const float* wv = (const float*)d_in[5];
    const float* bv = (const float*)d_in[6];
    const float* wo = (const float*)d_in[7];
    const float* bo = (const float*)d_in[8];

    u16* xb   = (u16*)d_ws;                 // 4M  : x f16
    u16* wb   = xb  + ((size_t)4  << 20);   // 4M  : wq,wk,wv,wo f16
    u16* qk   = wb  + ((size_t)4  << 20);   // 8M  : q,k  [B,H,S,HD] (q pre-scaled)
    u16* vtw  = qk  + ((size_t)8  << 20);   // 4M  : v^T  [B,H,HD,S] (kv-perm tiles)
    u16* ctxb = vtw + ((size_t)4  << 20);   // 4M  : ctx  [B,S,D]

    cast_all<<<4096, 256, 0, stream>>>(x, wq, wk, wv, wo, xb, wb);

    // fused QKV: N-space = 3*1024; V written transposed+permuted
    gemm_mfma<1><<<dim3(24, 32), 512, 0, stream>>>(
        xb, wb, bq, bk, bv, nullptr, qk, vtw);

    attn_mfma<<<dim3(16, 32), 512, 0, stream>>>(
        qk, qk + ((size_t)4 << 20), vtw, ctxb);

    gemm_mfma<0><<<dim3(8, 32), 512, 0, stream>>>(
        ctxb, wb + ((size_t)3 << 20), bo, nullptr, nullptr,
        (float*)d_out, nullptr, nullptr);
}

// Round 8
// 178.862 us; speedup vs baseline: 1.0594x; 1.0594x over previous
//
#include <hip/hip_runtime.h>
#include <math.h>
#include <stdint.h>

// Problem constants (B=2, S=2048, D=1024, H=16, HD=64)
constexpr int BB  = 2;
constexpr int SS  = 2048;
constexpr int DD  = 1024;
constexpr int HH  = 16;
constexpr int HDD = 64;
constexpr int MM  = BB * SS; // 4096

typedef uint16_t u16;
typedef __attribute__((ext_vector_type(4))) float    f32x4;
typedef __attribute__((ext_vector_type(8))) _Float16 f16x8;
typedef __attribute__((ext_vector_type(4))) _Float16 f16x4;
typedef __attribute__((ext_vector_type(8))) short    s16x8;
typedef __attribute__((ext_vector_type(4))) unsigned int u32x4;

__device__ __forceinline__ u16 to_f16(float f) {
    const _Float16 h = (_Float16)f;          // v_cvt_f16_f32, RNE
    return __builtin_bit_cast(u16, h);
}

__device__ __forceinline__ f32x4 mfma32(s16x8 a, s16x8 b, f32x4 c) {
    return __builtin_amdgcn_mfma_f32_16x16x32_f16(
        __builtin_bit_cast(f16x8, a), __builtin_bit_cast(f16x8, b), c, 0, 0, 0);
}
__device__ __forceinline__ f32x4 mfma32_ff(s16x8 a, f16x8 b, f32x4 c) {
    return __builtin_amdgcn_mfma_f32_16x16x32_f16(
        __builtin_bit_cast(f16x8, a), b, c, 0, 0, 0);
}

// async global->LDS, 16B per lane; LDS dest = wave-uniform base + lane*16
__device__ __forceinline__ void load_lds16(const void* g, void* l) {
    __builtin_amdgcn_global_load_lds(
        (const __attribute__((address_space(1))) void*)g,
        (__attribute__((address_space(3))) void*)l, 16, 0, 0);
}

// ---------------------------------------------------------------------------
// fp32 -> fp16 cast, all 5 tensors in one launch.
// blocks 0..2047: x (4M elems); blocks 2048..4095: wq,wk,wv,wo (1M each).
// ---------------------------------------------------------------------------
__global__ __launch_bounds__(256) void cast_all(
    const float* __restrict__ x,
    const float* __restrict__ w0, const float* __restrict__ w1,
    const float* __restrict__ w2, const float* __restrict__ w3,
    u16* __restrict__ xb, u16* __restrict__ wb)
{
    const int blk = blockIdx.x, tid = threadIdx.x;
    const float* src; u16* dst; int idx;
    if (blk < 2048) { src = x; dst = xb; idx = blk * 256 + tid; }
    else {
        const int b2 = blk - 2048, which = b2 >> 9;
        src = (which == 0) ? w0 : (which == 1) ? w1 : (which == 2) ? w2 : w3;
        dst = wb + ((size_t)which << 20);
        idx = (b2 & 511) * 256 + tid;
    }
    const float4* in4 = (const float4*)src;
    const float4 a = in4[idx * 2], b = in4[idx * 2 + 1];
    s16x8 v;
    v[0] = (short)to_f16(a.x); v[1] = (short)to_f16(a.y);
    v[2] = (short)to_f16(a.z); v[3] = (short)to_f16(a.w);
    v[4] = (short)to_f16(b.x); v[5] = (short)to_f16(b.y);
    v[6] = (short)to_f16(b.z); v[7] = (short)to_f16(b.w);
    *(s16x8*)(dst + (size_t)idx * 8) = v;
}

// ---------------------------------------------------------------------------
// Group K-loop, BK=64: same staged bytes / ds_read bytes / MFMA count per K
// as BK=32, but HALF the barrier iterations (8 vs 16 per group). R3 verified.
// LDS layout per group: [buf][128 rows][8 x 16B units]; physical unit pu
// at row r holds global unit pu ^ (r&7) -> frag ds_read_b128 is 2-way max.
// ---------------------------------------------------------------------------
template <bool SWAP>
__device__ __forceinline__ void kloop64(
    const u16* __restrict__ Ag, const u16* __restrict__ Wg,
    u16* Abase, u16* Bbase, const int w4,
    const int lane, const int wm, const int wn, f32x4 (&acc)[4][4])
{
    const int lt = lane & 15, quad = lane >> 4;
    const int cb = w4 * 4;                      // wave's first chunk

#define STG64(buf_, ko_) do {                                              \
    _Pragma("unroll")                                                      \
    for (int c = 0; c < 4; ++c) {                                          \
        load_lds16(Ag + (size_t)((cb + c) * 8) * 1024 + (ko_),             \
                   Abase + (buf_) * 8192 + (cb + c) * 512);                \
        load_lds16(Wg + (size_t)((cb + c) * 8) * 1024 + (ko_),             \
                   Bbase + (buf_) * 8192 + (cb + c) * 512);                \
    } } while (0)

    STG64(0, 0);                                 // prologue -> buffer 0

#pragma unroll 1
    for (int it = 0; it < 8; ++it) {
        const int buf = it & 1;
        __syncthreads();                         // drains this buffer's loads
        if (it < 7) STG64(buf ^ 1, (it + 1) * 64);
        const u16* Acur = Abase + buf * 8192;
        const u16* Bcur = Bbase + buf * 8192;

        s16x8 af[2][4], bf[2][4];
#pragma unroll
        for (int kk = 0; kk < 2; ++kk) {
#pragma unroll
            for (int i = 0; i < 4; ++i) {
                const int row = wm + i * 16 + lt;
                af[kk][i] = *(const s16x8*)(Acur + row * 64 +
                                (((kk * 4 + quad) ^ (row & 7)) * 8));
            }
#pragma unroll
            for (int j = 0; j < 4; ++j) {
                const int row = wn + j * 16 + lt;
                bf[kk][j] = *(const s16x8*)(Bcur + row * 64 +
                                (((kk * 4 + quad) ^ (row & 7)) * 8));
            }
        }
#pragma unroll
        for (int i = 0; i < 4; ++i)
#pragma unroll
            for (int j = 0; j < 4; ++j) {
                if (SWAP) {
                    acc[i][j] = mfma32(bf[0][j], af[0][i], acc[i][j]);
                    acc[i][j] = mfma32(bf[1][j], af[1][i], acc[i][j]);
                } else {
                    acc[i][j] = mfma32(af[0][i], bf[0][j], acc[i][j]);
                    acc[i][j] = mfma32(af[1][i], bf[1][j], acc[i][j]);
                }
            }
    }
#undef STG64
}

// ---------------------------------------------------------------------------
// Split-K MFMA GEMM: C = A @ W^T + bias.  A:[M,K] f16, W:[N,K] f16.
// 512 threads = 2 groups x 4 waves; group g computes K-half g (KH=512,
// 8 BK=64 iters) into fp32 partials; merged via a conflict-free LDS
// overlay; group 0 runs the epilogue.
// Grid mapping: IDENTITY (R6-verified). The R3-R5 "T1" swizzle chunked each
// XCD across ALL 24 W-panels (6MB > 4MB L2) -> FETCH doubled 40->80MB.
// Default round-robin keeps each XCD's W+A set < 4MB L2.
// MODE 1 (QKV): Q (SWAP) pre-scaled by 0.125 (exact pow2; do NOT fold
// log2e -- R4 numerics failure); K (SWAP) unscaled; V (no swap) written
// [B,H,HD,S] with kv-perm baked into each 64-wide s-tile.
// MODE 0 (SWAP): single matrix, fp32 [M,N] out, float4 stores.
// ---------------------------------------------------------------------------
template <int MODE>
__global__ __launch_bounds__(512) void gemm_mfma(
    const u16* __restrict__ A, const u16* __restrict__ Wb,
    const float* __restrict__ b0, const float* __restrict__ b1,
    const float* __restrict__ b2,
    float* __restrict__ outf, u16* __restrict__ outq, u16* __restrict__ outv)
{
    // 128KB: A [grp][buf][128x64] (64KB) | B same (64KB); fp32 overlay reuses
    __shared__ u16 smem[65536];

    const int tid = threadIdx.x, lane = tid & 63, wid = tid >> 6;
    const int grp = wid >> 2, w4 = wid & 3;
    const int quad = lane >> 4;

    const int bm = blockIdx.y * 128;
    const int nb = blockIdx.x * 128;      // col in (possibly concatenated) N space
    const int which = nb >> 10;           // 0..2 in MODE 1, always 0 in MODE 0
    const int ncol  = nb & 1023;
    const u16* Wblk = Wb + ((size_t)which << 20) + (size_t)ncol * 1024;

    // staging per-thread base (see kloop64 header)
    const int rbase = lane >> 3;
    const int gu    = (lane & 7) ^ rbase;
    const u16* Ag = A    + (size_t)(bm + rbase) * 1024 + grp * 512 + gu * 8;
    const u16* Wg = Wblk + (size_t)rbase        * 1024 + grp * 512 + gu * 8;
    u16* Abase = smem + grp * 16384;
    u16* Bbase = smem + 32768 + grp * 16384;

    f32x4 acc[4][4];
#pragma unroll
    for (int i = 0; i < 4; ++i)
#pragma unroll
        for (int j = 0; j < 4; ++j) { f32x4 z = {0.f, 0.f, 0.f, 0.f}; acc[i][j] = z; }

    const int wm = (w4 >> 1) * 64, wn = (w4 & 1) * 64;
    const bool swap = (MODE == 0) || (which < 2);
    if (swap) kloop64<true >(Ag, Wg, Abase, Bbase, w4, lane, wm, wn, acc);
    else      kloop64<false>(Ag, Wg, Abase, Bbase, w4, lane, wm, wn, acc);

    // ---- merge K-half partials via LDS overlay (exact fp32 adds) ----
    __syncthreads();   // all staging reads done; safe to overlay smem
    float* rp = (float*)smem;
    const int slot = (w4 * 64 + lane) * 4;
    if (grp == 1) {
#pragma unroll
        for (int i = 0; i < 4; ++i)
#pragma unroll
            for (int j = 0; j < 4; ++j)
                *(f32x4*)(rp + (i * 4 + j) * 1024 + slot) = acc[i][j];
    }
    __syncthreads();
    if (grp != 0) return;
#pragma unroll
    for (int i = 0; i < 4; ++i)
#pragma unroll
        for (int j = 0; j < 4; ++j)
            acc[i][j] += *(const f32x4*)(rp + (i * 4 + j) * 1024 + slot);

    if (MODE == 0) {
        // C^T: rows = n (tile j, quad*4+r), cols = m (tile i, lane&15)
#pragma unroll
        for (int j = 0; j < 4; ++j) {
            const int n0 = nb + wn + 16 * j + quad * 4;
            const float4 bv = *(const float4*)&b0[n0];
#pragma unroll
            for (int i = 0; i < 4; ++i) {
                const int m = bm + wm + 16 * i + (lane & 15);
                f32x4 w = acc[i][j];
                w[0] += bv.x; w[1] += bv.y; w[2] += bv.z; w[3] += bv.w;
                *(f32x4*)&outf[(size_t)m * 1024 + n0] = w;
            }
        }
    } else if (which < 2) {
        // Q/K (swapped): 4 contiguous hd per lane -> f16x4 stores
        const float* bias = which ? b1 : b0;
        const float scale = which ? 1.0f : 0.125f;   // fold 1/sqrt(HD) into Q
        u16* outb = outq + ((size_t)which << 22);
        const int h = (ncol + wn) >> 6;
#pragma unroll
        for (int j = 0; j < 4; ++j) {
            const int nl0 = ncol + wn + 16 * j + quad * 4;
            const float4 bv = *(const float4*)&bias[nl0];
            const int hd0 = 16 * j + quad * 4;
#pragma unroll
            for (int i = 0; i < 4; ++i) {
                const int m = bm + wm + 16 * i + (lane & 15);
                const int b_ = m >> 11, s = m & 2047;
                f16x4 w;
                w[0] = (_Float16)((acc[i][j][0] + bv.x) * scale);
                w[1] = (_Float16)((acc[i][j][1] + bv.y) * scale);
                w[2] = (_Float16)((acc[i][j][2] + bv.z) * scale);
                w[3] = (_Float16)((acc[i][j][3] + bv.w) * scale);
                *(f16x4*)&outb[(((size_t)(b_ * HH + h)) * SS + s) * HDD + hd0] = w;
            }
        }
    } else {
        // V (unswapped): rows = s (kv), cols = hd. kv = i*16 + quad*4 + r
        // -> p = (i>>1)*32 + quad*8 + (i&1)*4 + r (contiguous in r).
        const int kt = ((bm + wm) & 2047) >> 6;
        const int b_ = (bm + wm) >> 11;
#pragma unroll
        for (int j = 0; j < 4; ++j) {
            const int nl = ncol + wn + 16 * j + (lane & 15);
            const float bb = b2[nl];
            const int h = nl >> 6, hd = nl & 63;
            u16* vrow = outv + (((size_t)(b_ * HH + h)) * HDD + hd) * SS + kt * 64;
#pragma unroll
            for (int i = 0; i < 4; ++i) {
                const int p0 = (i >> 1) * 32 + quad * 8 + (i & 1) * 4;
                f16x4 w;
                w[0] = (_Float16)(acc[i][j][0] + bb);
                w[1] = (_Float16)(acc[i][j][1] + bb);
                w[2] = (_Float16)(acc[i][j][2] + bb);
                w[3] = (_Float16)(acc[i][j][3] + bb);
                *(f16x4*)&vrow[p0] = w;
            }
        }
    }
}

// ---------------------------------------------------------------------------
// MFMA flash attention v5 (R8): R6 structure + Q-tile 256 (T15 reverted --
// R7 regressed 44.2->47). Each wave owns FOUR 16-row q-subtiles; grid
// halves to 256 blocks (= exactly 1/CU, no tail). Per iteration the SAME
// 8 K-reads + 8 V-reads now feed 2x the MFMAs (32 QK + 8 l + 32 PV), and
// total barrier crossings per FLOP halve -- the same lever class as R3's
// proven BK=64 QKV win. S lives only per half-tile (j=0,1 then j=2,3) to
// bound VGPR (~210 peak -> launch_bounds(512,2), NOT (512,4) which would
// cap at 128 and spill). XCD-grouped swizzle kept (R6: FETCH 69.7->12.3MB).
// ---------------------------------------------------------------------------
__global__ __launch_bounds__(512, 2) void attn_mfma(
    const u16* __restrict__ Q, const u16* __restrict__ Kg,
    const u16* __restrict__ Vt, u16* __restrict__ ctx)
{
    // main loop: K [grp][2][64x64] (32KB) + V same (32KB) = 64KB;
    // epilogue overlays 70KB (16 merge slots x 1088 floats + l).
    __shared__ u16 smem[35840];

    const int tid = threadIdx.x, lane = tid & 63, wid = tid >> 6;
    const int grp = wid >> 2, w4 = wid & 3;
    const int quad = lane >> 4, lt = lane & 15, sw = lane & 7;

    // bijective XCD-group swizzle: 256 blocks = 8 XCD x (4 heads x 8 qb)
    const int orig   = blockIdx.y * 8 + blockIdx.x;
    const int xcd    = orig & 7, within = orig >> 3;
    const int bh     = xcd * 4 + (within >> 3);
    const int q0     = (within & 7) * 256;

    const u16* Qb = Q  + (size_t)bh * SS * HDD;
    const u16* Kb = Kg + (size_t)bh * SS * HDD + (size_t)grp * 1024 * HDD;
    const u16* Vb = Vt + (size_t)bh * HDD * SS + grp * 1024;

    u16* Kbase = smem + grp * 8192;            // + buf*4096
    u16* Vbase = smem + 16384 + grp * 8192;

    // Q B-frags for FOUR q-subtiles: n=q=lane&15, k=quad*8+{0..7} (+32 c1)
    const int qa = q0 + w4 * 64 + lt;
    s16x8 bq[4][2];
#pragma unroll
    for (int s = 0; s < 4; ++s) {
        bq[s][0] = *(const s16x8*)(Qb + (size_t)(qa + 16 * s) * HDD + quad * 8);
        bq[s][1] = *(const s16x8*)(Qb + (size_t)(qa + 16 * s) * HDD + 32 + quad * 8);
    }

    f32x4 o[4][4];        // O^T per subtile: C[m=hd(16m+quad*4+r)][n=q=lt]
    f32x4 l4[4];
#pragma unroll
    for (int s = 0; s < 4; ++s) {
        f32x4 z = {0.f, 0.f, 0.f, 0.f};
        l4[s] = z;
#pragma unroll
        for (int m = 0; m < 4; ++m) o[s][m] = z;
    }
    const s16x8 ones = {15360, 15360, 15360, 15360,
                        15360, 15360, 15360, 15360};  // f16 1.0 x8

    // staging: chunk c (0..7) = 1KB = 8 rows of 128B;
    // physical unit p=c*64+lane -> row p>>3, holds global unit (lane&7)^(row&7)
    const int c0 = w4 * 2, c1 = c0 + 1;
    const int r0 = (c0 * 64 + lane) >> 3, lu0 = ((lane & 7) ^ (r0 & 7));
    const int r1 = (c1 * 64 + lane) >> 3, lu1 = ((lane & 7) ^ (r1 & 7));
    const u16* Kp0 = Kb + (size_t)r0 * HDD + lu0 * 8;
    const u16* Kp1 = Kb + (size_t)r1 * HDD + lu1 * 8;
    const u16* Vp0 = Vb + (size_t)r0 * SS + lu0 * 8;
    const u16* Vp1 = Vb + (size_t)r1 * SS + lu1 * 8;

    // prologue: group's tile 0 -> buffer 0
    load_lds16(Kp0, Kbase + c0 * 512);
    load_lds16(Kp1, Kbase + c1 * 512);
    load_lds16(Vp0, Vbase + c0 * 512);
    load_lds16(Vp1, Vbase + c1 * 512);

#pragma unroll 1
    for (int kt = 0; kt < 16; ++kt) {
        const int buf = kt & 1;
        __syncthreads();   // drains this buffer's loads (in flight one iter)

        if (kt + 1 < 16) {   // prefetch group's next tile into other buffer
            const int nb_ = (buf ^ 1) * 4096;
            load_lds16(Kp0 + (size_t)(kt + 1) * 64 * HDD, Kbase + nb_ + c0 * 512);
            load_lds16(Kp1 + (size_t)(kt + 1) * 64 * HDD, Kbase + nb_ + c1 * 512);
            load_lds16(Vp0 + (kt + 1) * 64, Vbase + nb_ + c0 * 512);
            load_lds16(Vp1 + (kt + 1) * 64, Vbase + nb_ + c1 * 512);
        }
        const u16* Kbuf = Kbase + buf * 4096;
        const u16* Vbuf = Vbase + buf * 4096;

        // ---- S^T + exp/pack per kv half-tile (keys 0..31 then 32..63);
        // S scoped to the half so only 8 f32x4 live at once ----
        f16x8 P[4][2];
#pragma unroll
        for (int h = 0; h < 2; ++h) {
            f32x4 S[4][2];
#pragma unroll
            for (int j = 0; j < 2; ++j) {
                const int row = (h * 2 + j) * 16 + lt;     // key row in tile
                const s16x8 ak0 = *(const s16x8*)(Kbuf + (size_t)row * 64 + ((quad    ) ^ sw) * 8);
                const s16x8 ak1 = *(const s16x8*)(Kbuf + (size_t)row * 64 + ((quad + 4) ^ sw) * 8);
#pragma unroll
                for (int s = 0; s < 4; ++s) {
                    f32x4 z = {0.f, 0.f, 0.f, 0.f};
                    z = mfma32(ak0, bq[s][0], z);
                    z = mfma32(ak1, bq[s][1], z);
                    S[s][j] = z;
                }
            }
#pragma unroll
            for (int s = 0; s < 4; ++s) {
                u32x4 u;
                u[0] = __builtin_bit_cast(unsigned int, __builtin_amdgcn_cvt_pkrtz(__expf(S[s][0][0]), __expf(S[s][0][1])));
                u[1] = __builtin_bit_cast(unsigned int, __builtin_amdgcn_cvt_pkrtz(__expf(S[s][0][2]), __expf(S[s][0][3])));
                u[2] = __builtin_bit_cast(unsigned int, __builtin_amdgcn_cvt_pkrtz(__expf(S[s][1][0]), __expf(S[s][1][1])));
                u[3] = __builtin_bit_cast(unsigned int, __builtin_amdgcn_cvt_pkrtz(__expf(S[s][1][2]), __expf(S[s][1][3])));
                P[s][h] = __builtin_bit_cast(f16x8, u);
            }
        }

        // ---- l via ones-MFMA: C[m][q] = sum_k P[k][q] ----
#pragma unroll
        for (int s = 0; s < 4; ++s) {
            l4[s] = mfma32_ff(ones, P[s][0], l4[s]);
            l4[s] = mfma32_ff(ones, P[s][1], l4[s]);
        }

        // ---- O^T += Vt·P^T : V frags shared across the 4 subtiles ----
#pragma unroll
        for (int m = 0; m < 4; ++m) {
            const int row = m * 16 + lt;               // hd row in Vt tile
            const s16x8 v0 = *(const s16x8*)(Vbuf + (size_t)row * 64 + ((quad    ) ^ sw) * 8);
            const s16x8 v1 = *(const s16x8*)(Vbuf + (size_t)row * 64 + ((quad + 4) ^ sw) * 8);
#pragma unroll
            for (int s = 0; s < 4; ++s) {
                o[s][m] = mfma32_ff(v0, P[s][0], o[s][m]);
                o[s][m] = mfma32_ff(v1, P[s][1], o[s][m]);
            }
        }
    }

    // ---- cross-group merge via LDS (plain sums; no-max softmax) ----
    // layout: float O[slot=w4*4+s][q=16][hd=64 pad->68], then l[slot][16]
    __syncthreads();   // all staging reads done; safe to overlay smem
    float* ep = (float*)smem;
    float* lp = ep + 16 * 1088;
    if (grp == 1) {
#pragma unroll
        for (int s = 0; s < 4; ++s) {
            float* base = ep + (w4 * 4 + s) * 1088 + lt * 68 + quad * 4;
#pragma unroll
            for (int m = 0; m < 4; ++m)
                *(f32x4*)(base + m * 16) = o[s][m];
        }
        if (quad == 0) {
#pragma unroll
            for (int s = 0; s < 4; ++s)
                lp[(w4 * 4 + s) * 16 + lt] = l4[s][0];
        }
    }
    __syncthreads();
    if (grp == 0) {
        const int b_ = bh >> 4, h = bh & 15;
#pragma unroll
        for (int s = 0; s < 4; ++s) {
            const float inv = 1.f / (l4[s][0] + lp[(w4 * 4 + s) * 16 + lt]);
            const float* base = ep + (w4 * 4 + s) * 1088 + lt * 68 + quad * 4;
            const int s_idx = q0 + w4 * 64 + s * 16 + lt;
            u16* orow = ctx + ((size_t)(b_ * SS + s_idx)) * DD + h * HDD;
#pragma unroll
            for (int m = 0; m < 4; ++m) {
                const f32x4 part = *(const f32x4*)(base + m * 16);
                f16x4 w;
#pragma unroll
                for (int r = 0; r < 4; ++r)
                    w[r] = (_Float16)((o[s][m][r] + part[r]) * inv);
                *(f16x4*)(orow + m * 16 + quad * 4) = w;
            }
        }
    }
}

// ---------------------------------------------------------------------------
extern "C" void kernel_launch(void* const* d_in, const int* in_sizes, int n_in,
                              void* d_out, int out_size, void* d_ws, size_t ws_size,
                              hipStream_t stream)
{
    const float* x  = (const float*)d_in[0];
    const float* wq = (const float*)d_in[1];
    const float* bq = (const float*)d_in[2];
    const float* wk = (const float*)d_in[3];
    const float* bk = (const float*)d_in[4];
    const float* wv = (const float*)d_in[5];
    const float* bv = (const float*)d_in[6];
    const float* wo = (const float*)d_in[7];
    const float* bo = (const float*)d_in[8];

    u16* xb   = (u16*)d_ws;                 // 4M  : x f16
    u16* wb   = xb  + ((size_t)4  << 20);   // 4M  : wq,wk,wv,wo f16
    u16* qk   = wb  + ((size_t)4  << 20);   // 8M  : q,k  [B,H,S,HD] (q pre-scaled)
    u16* vtw  = qk  + ((size_t)8  << 20);   // 4M  : v^T  [B,H,HD,S] (kv-perm tiles)
    u16* ctxb = vtw + ((size_t)4  << 20);   // 4M  : ctx  [B,S,D]

    cast_all<<<4096, 256, 0, stream>>>(x, wq, wk, wv, wo, xb, wb);

    // fused QKV: N-space = 3*1024; V written transposed+permuted
    gemm_mfma<1><<<dim3(24, 32), 512, 0, stream>>>(
        xb, wb, bq, bk, bv, nullptr, qk, vtw);

    // Q-tile 256: 256 blocks = 8 q-blocks x 32 bh
    attn_mfma<<<dim3(8, 32), 512, 0, stream>>>(
        qk, qk + ((size_t)4 << 20), vtw, ctxb);

    gemm_mfma<0><<<dim3(8, 32), 512, 0, stream>>>(
        ctxb, wb + ((size_t)3 << 20), bo, nullptr, nullptr,
        (float*)d_out, nullptr, nullptr);
}